// Round 1
// baseline (15556.288 us; speedup 1.0000x reference)
//
#include <hip/hip_runtime.h>
#include <math.h>

#define B_   8192
#define N_   68
#define FIN  2
#define F_   128
#define C_   16
#define E_   272

// d_out flat layout (fp32), reference tuple order:
#define OUT_OFF  0                              // [B,16,128]
#define ADJ_OFF  (B_*C_*F_)                     // 16777216, [B,16,16]
#define LINK_IDX (ADJ_OFF + B_*C_*C_)           // 18874368
#define ENT_IDX  (LINK_IDX + 1)                 // 18874369
#define POS_OFF  (ENT_IDX + 1)                  // 18874370, [B,68,2]

// ws layout: [0..131071] doubles: 8192*2 block partials (link, ent)
//            [131072.. ] ints: csr offs[69] + srcs[272]
#define WS_INT_OFF 131072

#define RELU(v) ((v) > 0.f ? (v) : 0.f)

__global__ void prep_kernel(const int* __restrict__ edge_index, int* __restrict__ csr) {
  __shared__ int src_s[E_], dst_s[E_], cnt[N_], offs[N_ + 1];
  int t = threadIdx.x;
  for (int e = t; e < E_; e += blockDim.x) { src_s[e] = edge_index[e]; dst_s[e] = edge_index[E_ + e]; }
  for (int n = t; n < N_; n += blockDim.x) cnt[n] = 0;
  __syncthreads();
  if (t == 0) {
    for (int e = 0; e < E_; ++e) cnt[dst_s[e]]++;
    offs[0] = 0;
    for (int n = 0; n < N_; ++n) offs[n + 1] = offs[n] + cnt[n];
    for (int n = 0; n < N_; ++n) cnt[n] = offs[n];
    for (int e = 0; e < E_; ++e) { int d = dst_s[e]; csr[N_ + 1 + cnt[d]++] = src_s[e]; }
    for (int n = 0; n <= N_; ++n) csr[n] = offs[n];
  }
}

// fused per-layer GEMM: Out[n][f] = relu_or_partial( G@Wr^T + H@Wo^T + b )
// 2 K-passes of 64 so W rows (128 floats) stay in VGPRs across the 17-row loop.
__device__ __forceinline__ void gemm_layer(
    const float* __restrict__ Gin, const float* __restrict__ Hin, float* __restrict__ Out,
    const float* __restrict__ Wr, const float* __restrict__ Wo, const float* __restrict__ bb,
    int f, int ng)
{
  float bv = bb[f];
  for (int p = 0; p < 2; ++p) {
    int k0 = p * 64;
    float4 WR[16], WO[16];
#pragma unroll
    for (int j = 0; j < 16; ++j) {
      WR[j] = *(const float4*)&Wr[f * F_ + k0 + 4 * j];
      WO[j] = *(const float4*)&Wo[f * F_ + k0 + 4 * j];
    }
    for (int i = 0; i < 17; ++i) {
      int n = ng * 17 + i;
      const float4* g4 = (const float4*)&Gin[n * F_ + k0];
      const float4* h4 = (const float4*)&Hin[n * F_ + k0];
      float a0 = 0, a1 = 0, a2 = 0, a3 = 0, c0 = 0, c1 = 0, c2 = 0, c3 = 0;
#pragma unroll
      for (int j = 0; j < 16; ++j) {
        float4 g = g4[j], h = h4[j];
        a0 += g.x * WR[j].x; a1 += g.y * WR[j].y; a2 += g.z * WR[j].z; a3 += g.w * WR[j].w;
        c0 += h.x * WO[j].x; c1 += h.y * WO[j].y; c2 += h.z * WO[j].z; c3 += h.w * WO[j].w;
      }
      float sum = ((a0 + a1) + (a2 + a3)) + ((c0 + c1) + (c2 + c3));
      if (p == 0) {
        Out[n * F_ + f] = sum;
      } else {
        float v = Out[n * F_ + f] + sum + bv;
        Out[n * F_ + f] = RELU(v);
      }
    }
  }
}

__launch_bounds__(512, 2)
__global__ void fused_kernel(
    const float* __restrict__ x, const float* __restrict__ adj, const float* __restrict__ s,
    const float* __restrict__ pos,
    const float* __restrict__ W1r, const float* __restrict__ W1o, const float* __restrict__ b1,
    const float* __restrict__ W2r, const float* __restrict__ W2o, const float* __restrict__ b2,
    const float* __restrict__ W3r, const float* __restrict__ W3o, const float* __restrict__ b3,
    float* __restrict__ out, const int* __restrict__ csr, double* __restrict__ partials)
{
  __shared__ float A[N_ * F_];    // h1, later h3
  __shared__ float Bf[N_ * F_];   // agg buffers, later tmat
  __shared__ float Cb[N_ * F_];   // h2, later tmat storage
  __shared__ float ssm[N_ * 17];  // softmax(s), padded stride 17
  __shared__ float xb[N_ * FIN], axb[N_ * FIN];
  __shared__ int offs[N_ + 1], srcs[E_];
  __shared__ double red[16];

  const int b = blockIdx.x;
  const int tid = threadIdx.x;
  const int f = tid & 127;
  const int ng = tid >> 7;  // 0..3

  for (int i = tid; i < N_ + 1; i += 512) offs[i] = csr[i];
  for (int i = tid; i < E_; i += 512) srcs[i] = csr[N_ + 1 + i];
  for (int i = tid; i < N_ * FIN; i += 512) xb[i] = x[(size_t)b * N_ * FIN + i];
  __syncthreads();

  // layer-1 edge aggregation on [68,2]
  if (tid < N_) {
    float a0 = 0, a1 = 0;
    for (int e = offs[tid]; e < offs[tid + 1]; ++e) {
      int sr = srcs[e];
      a0 += xb[sr * 2]; a1 += xb[sr * 2 + 1];
    }
    axb[tid * 2] = a0; axb[tid * 2 + 1] = a1;
  }
  __syncthreads();

  // layer 1 -> A
  {
    float wr0 = W1r[f * 2], wr1 = W1r[f * 2 + 1];
    float wo0 = W1o[f * 2], wo1 = W1o[f * 2 + 1];
    float bv = b1[f];
    for (int i = 0; i < 17; ++i) {
      int n = ng * 17 + i;
      float v = axb[n * 2] * wr0 + axb[n * 2 + 1] * wr1 + xb[n * 2] * wo0 + xb[n * 2 + 1] * wo1 + bv;
      A[n * F_ + f] = RELU(v);
    }
  }
  __syncthreads();

  // agg(h1) -> Bf
  for (int i = 0; i < 17; ++i) {
    int n = ng * 17 + i;
    float acc = 0;
    for (int e = offs[n]; e < offs[n + 1]; ++e) acc += A[srcs[e] * F_ + f];
    Bf[n * F_ + f] = acc;
  }
  __syncthreads();

  // layer 2: Cb = relu(Bf@W2r^T + A@W2o^T + b2)
  gemm_layer(Bf, A, Cb, W2r, W2o, b2, f, ng);
  __syncthreads();

  // agg(h2) -> Bf
  for (int i = 0; i < 17; ++i) {
    int n = ng * 17 + i;
    float acc = 0;
    for (int e = offs[n]; e < offs[n + 1]; ++e) acc += Cb[srcs[e] * F_ + f];
    Bf[n * F_ + f] = acc;
  }
  __syncthreads();

  // layer 3: A = relu(Bf@W3r^T + Cb@W3o^T + b3)   (A = h3)
  gemm_layer(Bf, Cb, A, W3r, W3o, b3, f, ng);
  __syncthreads();

  // softmax rows of s -> ssm, plus entropy partial
  float entPart = 0.f;
  if (tid < N_) {
    const float* srow = &s[((size_t)b * N_ + tid) * C_];
    float sv[16];
    float mx = -1e30f;
#pragma unroll
    for (int c2 = 0; c2 < 16; ++c2) { sv[c2] = srow[c2]; mx = fmaxf(mx, sv[c2]); }
    float sum = 0;
#pragma unroll
    for (int c2 = 0; c2 < 16; ++c2) { sv[c2] = expf(sv[c2] - mx); sum += sv[c2]; }
    float inv = 1.f / sum;
#pragma unroll
    for (int c2 = 0; c2 < 16; ++c2) {
      float pv = sv[c2] * inv;
      ssm[tid * 17 + c2] = pv;
      entPart -= pv * logf(pv + 1e-15f);
    }
  }
  __syncthreads();

  // out[b,c,f] = sum_n ssm[n,c] * h3[n,f]
  for (int c2 = ng; c2 < C_; c2 += 4) {
    float acc = 0;
    for (int n = 0; n < N_; ++n) acc += ssm[n * 17 + c2] * A[n * F_ + f];
    out[OUT_OFF + ((size_t)b * C_ + c2) * F_ + f] = acc;
  }

  // tmat[n,k] = sum_m adj[n,m]*ssm[m,k]  -> stored in Cb[0..68*16)
  const float* adjb = &adj[(size_t)b * N_ * N_];
  {
    int k = tid & 15, nq = tid >> 4;  // nq 0..31
    for (int n = nq; n < N_; n += 32) {
      float acc = 0;
      for (int m = 0; m < N_; ++m) acc += adjb[n * N_ + m] * ssm[m * 17 + k];
      Cb[n * 16 + k] = acc;
    }
  }

  // link partial: sum (adj - ssm@ssm^T)^2
  float linkPart = 0.f;
  for (int q = tid; q < N_ * N_; q += 512) {
    int n = q / N_, m = q - n * N_;
    float dot = 0;
#pragma unroll
    for (int c2 = 0; c2 < 16; ++c2) dot += ssm[n * 17 + c2] * ssm[m * 17 + c2];
    float d = adjb[q] - dot;
    linkPart += d * d;
  }
  __syncthreads();

  // out_adj[b,c,k] = sum_n ssm[n,c]*tmat[n,k]
  if (tid < 256) {
    int c2 = tid >> 4, k = tid & 15;
    float acc = 0;
    for (int n = 0; n < N_; ++n) acc += ssm[n * 17 + c2] * Cb[n * 16 + k];
    out[ADJ_OFF + (size_t)b * 256 + c2 * 16 + k] = acc;
  }

  // pos passthrough
  for (int i = tid; i < N_ * FIN; i += 512)
    out[POS_OFF + (size_t)b * N_ * FIN + i] = pos[(size_t)b * N_ * FIN + i];

  // block reduction of loss partials (deterministic tree)
  double lk = (double)linkPart, en = (double)entPart;
  for (int o = 32; o > 0; o >>= 1) { lk += __shfl_down(lk, o); en += __shfl_down(en, o); }
  int wid = tid >> 6;
  if ((tid & 63) == 0) { red[wid] = lk; red[8 + wid] = en; }
  __syncthreads();
  if (tid == 0) {
    double L = 0, En = 0;
    for (int w = 0; w < 8; ++w) { L += red[w]; En += red[8 + w]; }
    partials[2 * b] = L;
    partials[2 * b + 1] = En;
  }
}

__global__ void finalize_kernel(const double* __restrict__ partials, float* __restrict__ out) {
  __shared__ double red[16];
  int tid = threadIdx.x;
  double L = 0, En = 0;
  for (int i = tid; i < B_; i += 512) { L += partials[2 * i]; En += partials[2 * i + 1]; }
  for (int o = 32; o > 0; o >>= 1) { L += __shfl_down(L, o); En += __shfl_down(En, o); }
  if ((tid & 63) == 0) { red[tid >> 6] = L; red[8 + (tid >> 6)] = En; }
  __syncthreads();
  if (tid == 0) {
    double Ls = 0, Es = 0;
    for (int w = 0; w < 8; ++w) { Ls += red[w]; Es += red[8 + w]; }
    out[LINK_IDX] = (float)(sqrt(Ls) / (double)((size_t)B_ * N_ * N_));
    out[ENT_IDX] = (float)(Es / (double)((size_t)B_ * N_));
  }
}

extern "C" void kernel_launch(void* const* d_in, const int* in_sizes, int n_in,
                              void* d_out, int out_size, void* d_ws, size_t ws_size,
                              hipStream_t stream) {
  const float* x   = (const float*)d_in[0];
  const int*   ei  = (const int*)d_in[1];
  const float* adj = (const float*)d_in[2];
  const float* s   = (const float*)d_in[3];
  const float* pos = (const float*)d_in[4];
  const float* W1r = (const float*)d_in[5];
  const float* W1o = (const float*)d_in[6];
  const float* b1  = (const float*)d_in[7];
  const float* W2r = (const float*)d_in[8];
  const float* W2o = (const float*)d_in[9];
  const float* b2  = (const float*)d_in[10];
  const float* W3r = (const float*)d_in[11];
  const float* W3o = (const float*)d_in[12];
  const float* b3  = (const float*)d_in[13];

  float* out = (float*)d_out;
  double* partials = (double*)d_ws;
  int* csr = (int*)((char*)d_ws + WS_INT_OFF);

  prep_kernel<<<1, 512, 0, stream>>>(ei, csr);
  fused_kernel<<<B_, 512, 0, stream>>>(x, adj, s, pos, W1r, W1o, b1,
                                       W2r, W2o, b2, W3r, W3o, b3,
                                       out, csr, partials);
  finalize_kernel<<<1, 512, 0, stream>>>(partials, out);
}

// Round 2
// 1016.565 us; speedup vs baseline: 15.3028x; 15.3028x over previous
//
#include <hip/hip_runtime.h>
#include <math.h>

#define B_   8192
#define N_   68
#define FIN  2
#define F_   128
#define C_   16
#define E_   272

// d_out flat layout (fp32), reference tuple order:
#define OUT_OFF  0                              // [B,16,128]
#define ADJ_OFF  (B_*C_*F_)                     // [B,16,16]
#define LINK_IDX (ADJ_OFF + B_*C_*C_)
#define ENT_IDX  (LINK_IDX + 1)
#define POS_OFF  (ENT_IDX + 1)                  // [B,68,2]

// ws layout: [0..131071] bytes: 8192*2 doubles (link, ent partials)
//            [131072..]  csr ints: offs[69] + srcs[272]
//            [133120..]  wcat bf16: 2 layers * 128 j * 256 k
#define WS_CSR_OFF  131072
#define WS_W_OFF    133120

typedef __attribute__((ext_vector_type(8))) short bf16x8;
typedef __attribute__((ext_vector_type(4))) float f32x4;

// XOR-swizzled byte address for [rows][128] bf16 tiles (row stride 256B).
// Breaks the all-lanes-same-bank pattern on ds_read_b128 (T2).
#define SWZ(row, colByte) (((row) * 256) + ((colByte) ^ (((row) & 7) << 4)))

__device__ __forceinline__ short bf16_rne(float x) {
  unsigned u = __builtin_bit_cast(unsigned, x);
  u += 0x7FFFu + ((u >> 16) & 1u);
  return (short)(u >> 16);
}
__device__ __forceinline__ float bf16_to_f(short h) {
  unsigned u = ((unsigned)(unsigned short)h) << 16;
  return __builtin_bit_cast(float, u);
}

__global__ void prep_kernel(const int* __restrict__ edge_index,
                            const float* __restrict__ W2r, const float* __restrict__ W2o,
                            const float* __restrict__ W3r, const float* __restrict__ W3o,
                            int* __restrict__ csr, short* __restrict__ wcat) {
  // weight conversion: wcat[layer][j][k]: k<128 -> Wrel[j][k], k>=128 -> Wroot[j][k-128]
  int gid = blockIdx.x * blockDim.x + threadIdx.x;
  for (int e = gid; e < 2 * F_ * 256; e += gridDim.x * blockDim.x) {
    int layer = e >> 15;
    int idx = e & 32767;
    int j = idx >> 8, k = idx & 255;
    const float* Wr = layer ? W3r : W2r;
    const float* Wo = layer ? W3o : W2o;
    float v = (k < F_) ? Wr[j * F_ + k] : Wo[j * F_ + (k - F_)];
    wcat[e] = bf16_rne(v);
  }
  __shared__ int src_s[E_], dst_s[E_], cnt[N_], offs[N_ + 1];
  if (blockIdx.x == 0) {
    int t = threadIdx.x;
    for (int e = t; e < E_; e += blockDim.x) { src_s[e] = edge_index[e]; dst_s[e] = edge_index[E_ + e]; }
    for (int n = t; n < N_; n += blockDim.x) cnt[n] = 0;
    __syncthreads();
    if (t == 0) {
      for (int e = 0; e < E_; ++e) cnt[dst_s[e]]++;
      offs[0] = 0;
      for (int n = 0; n < N_; ++n) offs[n + 1] = offs[n] + cnt[n];
      for (int n = 0; n < N_; ++n) cnt[n] = offs[n];
      for (int e = 0; e < E_; ++e) { int d = dst_s[e]; csr[N_ + 1 + cnt[d]++] = src_s[e]; }
      for (int n = 0; n <= N_; ++n) csr[n] = offs[n];
    }
  }
}

// One GraphConv layer on MFMA: Out = relu([A1|A2] @ wl^T + bias)
// A1/A2: [80][128] bf16 LDS (swizzled). wl: [128 j][256 k] bf16 global.
// Wave `j0/16` owns output features j0..j0+15; 5 M-tiles cover 68 node rows.
__device__ __forceinline__ void mfma_layer(const short* A1, const short* A2, short* Out,
    const short* __restrict__ wl, const float* __restrict__ bias,
    int l15, int lg, int j0, bool transposeOut)
{
  bf16x8 Bw[8];
#pragma unroll
  for (int ks = 0; ks < 8; ++ks)
    Bw[ks] = *(const bf16x8*)(wl + (j0 + l15) * 256 + ks * 32 + 8 * lg);
  float bv = bias[j0 + l15];
  for (int mt = 0; mt < 5; ++mt) {
    f32x4 acc = {0.f, 0.f, 0.f, 0.f};
#pragma unroll
    for (int ks = 0; ks < 4; ++ks)
      acc = __builtin_amdgcn_mfma_f32_16x16x32_bf16(
          *(const bf16x8*)((const char*)A1 + SWZ(mt * 16 + l15, ks * 64 + 16 * lg)),
          Bw[ks], acc, 0, 0, 0);
#pragma unroll
    for (int ks = 0; ks < 4; ++ks)
      acc = __builtin_amdgcn_mfma_f32_16x16x32_bf16(
          *(const bf16x8*)((const char*)A2 + SWZ(mt * 16 + l15, ks * 64 + 16 * lg)),
          Bw[4 + ks], acc, 0, 0, 0);
#pragma unroll
    for (int r = 0; r < 4; ++r) {
      int n = mt * 16 + lg * 4 + r;   // C/D: row=(lane>>4)*4+r, col=lane&15
      if (n < N_) {
        float v = acc[r] + bv;
        v = v > 0.f ? v : 0.f;
        short hv = bf16_rne(v);
        if (!transposeOut) *(short*)((char*)Out + SWZ(n, (j0 + l15) * 2)) = hv;
        else               *(short*)((char*)Out + SWZ(j0 + l15, n * 2)) = hv;
      }
    }
  }
}

__launch_bounds__(512, 2)
__global__ void fused_kernel(
    const float* __restrict__ x, const float* __restrict__ adj, const float* __restrict__ s,
    const float* __restrict__ pos,
    const float* __restrict__ W1r, const float* __restrict__ W1o, const float* __restrict__ b1,
    const float* __restrict__ b2, const float* __restrict__ b3,
    const short* __restrict__ wcat,
    float* __restrict__ out, const int* __restrict__ csr, double* __restrict__ partials)
{
  __shared__ __align__(16) short hA[80 * 128];     // h1 (then dead after layer2)
  __shared__ __align__(16) short hB[80 * 128];     // h2
  __shared__ __align__(16) short aggb[80 * 128];   // agg(h) staging
  __shared__ __align__(16) short h3T[128 * 128];   // h3 transposed [j][n]
  __shared__ __align__(16) short ssmT[16 * 128];   // softmax(s)^T [c][n], bf16
  __shared__ float ssm[N_ * 17];                   // softmax(s) fp32, padded stride
  __shared__ float tmat[N_ * C_];                  // adj @ ssm
  __shared__ float xb[N_ * FIN], axb[N_ * FIN];
  __shared__ int offs[N_ + 1], srcs[E_];
  __shared__ double red[16];

  const int b = blockIdx.x;
  const int tid = threadIdx.x;
  const int lane = tid & 63, wave = tid >> 6;
  const int l15 = lane & 15, lg = lane >> 4;
  const int f = tid & 127, ng = tid >> 7;   // 128 f-threads x 4 node-groups
  const int j0 = wave * 16;

  // ---- P0: stage csr/x, zero h3T (it is a B-operand: pads must be 0) ----
  for (int i = tid; i < N_ + 1; i += 512) offs[i] = csr[i];
  for (int i = tid; i < E_; i += 512) srcs[i] = csr[N_ + 1 + i];
  for (int i = tid; i < N_ * FIN; i += 512) xb[i] = x[(size_t)b * N_ * FIN + i];
  for (int i = tid; i < 128 * 128 / 2; i += 512) ((int*)h3T)[i] = 0;
  __syncthreads();

  // ---- P1: layer-1 edge aggregation on [68,2] ----
  if (tid < N_) {
    float a0 = 0, a1 = 0;
    for (int e = offs[tid]; e < offs[tid + 1]; ++e) {
      int sr = srcs[e];
      a0 += xb[sr * 2]; a1 += xb[sr * 2 + 1];
    }
    axb[tid * 2] = a0; axb[tid * 2 + 1] = a1;
  }
  __syncthreads();

  // ---- P2: layer 1 (K=2, VALU) -> hA bf16 ----
  {
    float wr0 = W1r[f * 2], wr1 = W1r[f * 2 + 1];
    float wo0 = W1o[f * 2], wo1 = W1o[f * 2 + 1];
    float bv = b1[f];
    for (int i = 0; i < 17; ++i) {
      int n = ng * 17 + i;
      float v = axb[n * 2] * wr0 + axb[n * 2 + 1] * wr1 + xb[n * 2] * wo0 + xb[n * 2 + 1] * wo1 + bv;
      v = v > 0.f ? v : 0.f;
      *(short*)((char*)hA + SWZ(n, f * 2)) = bf16_rne(v);
    }
  }
  __syncthreads();

  // ---- P3: agg(h1) -> aggb ----
  for (int i = 0; i < 17; ++i) {
    int n = ng * 17 + i;
    float acc = 0;
    for (int e = offs[n]; e < offs[n + 1]; ++e)
      acc += bf16_to_f(*(const short*)((const char*)hA + SWZ(srcs[e], f * 2)));
    *(short*)((char*)aggb + SWZ(n, f * 2)) = bf16_rne(acc);
  }
  __syncthreads();

  // ---- P4: layer 2 MFMA -> hB ----
  mfma_layer(aggb, hA, hB, wcat, b2, l15, lg, j0, false);
  __syncthreads();

  // ---- P5: agg(h2) -> aggb ----
  for (int i = 0; i < 17; ++i) {
    int n = ng * 17 + i;
    float acc = 0;
    for (int e = offs[n]; e < offs[n + 1]; ++e)
      acc += bf16_to_f(*(const short*)((const char*)hB + SWZ(srcs[e], f * 2)));
    *(short*)((char*)aggb + SWZ(n, f * 2)) = bf16_rne(acc);
  }
  __syncthreads();

  // ---- P6: layer 3 MFMA -> h3T (transposed store for pooling GEMM) ----
  mfma_layer(aggb, hB, h3T, wcat + 32768, b3, l15, lg, j0, true);
  __syncthreads();

  // ---- P7: softmax rows of s -> ssm (fp32) + entropy partial ----
  float entPart = 0.f;
  if (tid < N_) {
    const float* srow = &s[((size_t)b * N_ + tid) * C_];
    float sv[16];
    float mx = -1e30f;
#pragma unroll
    for (int c2 = 0; c2 < 16; ++c2) { sv[c2] = srow[c2]; mx = fmaxf(mx, sv[c2]); }
    float sum = 0;
#pragma unroll
    for (int c2 = 0; c2 < 16; ++c2) { sv[c2] = expf(sv[c2] - mx); sum += sv[c2]; }
    float inv = 1.f / sum;
#pragma unroll
    for (int c2 = 0; c2 < 16; ++c2) {
      float pv = sv[c2] * inv;
      ssm[tid * 17 + c2] = pv;
      entPart -= pv * logf(pv + 1e-15f);
    }
  }
  __syncthreads();

  const float* adjb = &adj[(size_t)b * N_ * N_];

  // ---- P8: build ssmT (bf16, zero-padded to K=96) + tmat = adj @ ssm ----
  for (int q = tid; q < 16 * 96; q += 512) {
    int c2 = q / 96, n = q - c2 * 96;
    float v = (n < N_) ? ssm[n * 17 + c2] : 0.f;
    *(short*)((char*)ssmT + SWZ(c2, n * 2)) = bf16_rne(v);
  }
  {
    int k = tid & 15, nq = tid >> 4;
    for (int n = nq; n < N_; n += 32) {
      float acc = 0;
      for (int m = 0; m < N_; ++m) acc += adjb[n * N_ + m] * ssm[m * 17 + k];
      tmat[n * 16 + k] = acc;
    }
  }
  __syncthreads();

  // ---- P9a: pooled out via MFMA: outT[j][c] = sum_n h3T[j][n]*ssm[n][c] ----
  {
    f32x4 acc = {0.f, 0.f, 0.f, 0.f};
#pragma unroll
    for (int ks = 0; ks < 3; ++ks) {
      bf16x8 a  = *(const bf16x8*)((const char*)h3T  + SWZ(j0 + l15, ks * 64 + 16 * lg));
      bf16x8 bb = *(const bf16x8*)((const char*)ssmT + SWZ(l15,      ks * 64 + 16 * lg));
      acc = __builtin_amdgcn_mfma_f32_16x16x32_bf16(a, bb, acc, 0, 0, 0);
    }
    // D: row=(lg*4+r) -> feature j0+lg*4+r ; col=l15 -> cluster c
    float4 st; st.x = acc[0]; st.y = acc[1]; st.z = acc[2]; st.w = acc[3];
    *(float4*)&out[OUT_OFF + (size_t)b * C_ * F_ + l15 * F_ + j0 + lg * 4] = st;
  }

  // ---- P9b: out_adj = ssm^T @ tmat ----
  if (tid < 256) {
    int c2 = tid >> 4, k = tid & 15;
    float acc = 0;
    for (int n = 0; n < N_; ++n) acc += ssm[n * 17 + c2] * tmat[n * 16 + k];
    out[ADJ_OFF + (size_t)b * 256 + c2 * 16 + k] = acc;
  }

  // ---- P9c: link partial ----
  float linkPart = 0.f;
  for (int q = tid; q < N_ * N_; q += 512) {
    int n = q / N_, m = q - n * N_;
    float dot = 0;
#pragma unroll
    for (int c2 = 0; c2 < 16; ++c2) dot += ssm[n * 17 + c2] * ssm[m * 17 + c2];
    float d = adjb[q] - dot;
    linkPart += d * d;
  }

  // ---- P9d: pos passthrough ----
  for (int i = tid; i < N_ * FIN; i += 512)
    out[POS_OFF + (size_t)b * N_ * FIN + i] = pos[(size_t)b * N_ * FIN + i];

  // ---- P9e: loss partial reduction (deterministic tree) ----
  double lk = (double)linkPart, en = (double)entPart;
  for (int o = 32; o > 0; o >>= 1) { lk += __shfl_down(lk, o); en += __shfl_down(en, o); }
  if ((tid & 63) == 0) { red[wave] = lk; red[8 + wave] = en; }
  __syncthreads();
  if (tid == 0) {
    double L = 0, En = 0;
    for (int w = 0; w < 8; ++w) { L += red[w]; En += red[8 + w]; }
    partials[2 * b] = L;
    partials[2 * b + 1] = En;
  }
}

__global__ void finalize_kernel(const double* __restrict__ partials, float* __restrict__ out) {
  __shared__ double red[16];
  int tid = threadIdx.x;
  double L = 0, En = 0;
  for (int i = tid; i < B_; i += 512) { L += partials[2 * i]; En += partials[2 * i + 1]; }
  for (int o = 32; o > 0; o >>= 1) { L += __shfl_down(L, o); En += __shfl_down(En, o); }
  if ((tid & 63) == 0) { red[tid >> 6] = L; red[8 + (tid >> 6)] = En; }
  __syncthreads();
  if (tid == 0) {
    double Ls = 0, Es = 0;
    for (int w = 0; w < 8; ++w) { Ls += red[w]; Es += red[8 + w]; }
    out[LINK_IDX] = (float)(sqrt(Ls) / (double)((size_t)B_ * N_ * N_));
    out[ENT_IDX] = (float)(Es / (double)((size_t)B_ * N_));
  }
}

extern "C" void kernel_launch(void* const* d_in, const int* in_sizes, int n_in,
                              void* d_out, int out_size, void* d_ws, size_t ws_size,
                              hipStream_t stream) {
  const float* x   = (const float*)d_in[0];
  const int*   ei  = (const int*)d_in[1];
  const float* adj = (const float*)d_in[2];
  const float* s   = (const float*)d_in[3];
  const float* pos = (const float*)d_in[4];
  const float* W1r = (const float*)d_in[5];
  const float* W1o = (const float*)d_in[6];
  const float* b1  = (const float*)d_in[7];
  const float* W2r = (const float*)d_in[8];
  const float* W2o = (const float*)d_in[9];
  const float* b2  = (const float*)d_in[10];
  const float* W3r = (const float*)d_in[11];
  const float* W3o = (const float*)d_in[12];
  const float* b3  = (const float*)d_in[13];

  float* out = (float*)d_out;
  double* partials = (double*)d_ws;
  int* csr = (int*)((char*)d_ws + WS_CSR_OFF);
  short* wcat = (short*)((char*)d_ws + WS_W_OFF);

  prep_kernel<<<65, 512, 0, stream>>>(ei, W2r, W2o, W3r, W3o, csr, wcat);
  fused_kernel<<<B_, 512, 0, stream>>>(x, adj, s, pos, W1r, W1o, b1, b2, b3,
                                       wcat, out, csr, partials);
  finalize_kernel<<<1, 512, 0, stream>>>(partials, out);
}

// Round 4
// 613.328 us; speedup vs baseline: 25.3637x; 1.6575x over previous
//
#include <hip/hip_runtime.h>
#include <math.h>

#define B_   8192
#define N_   68
#define FIN  2
#define F_   128
#define C_   16
#define E_   272

// d_out flat layout (fp32), reference tuple order:
#define OUT_OFF  0                              // [B,16,128]
#define ADJ_OFF  (B_*C_*F_)                     // [B,16,16]
#define LINK_IDX (ADJ_OFF + B_*C_*C_)
#define ENT_IDX  (LINK_IDX + 1)
#define POS_OFF  (ENT_IDX + 1)                  // [B,68,2]

// ws: [0,131072) partials (doubles, 8192*2)
//     [131072,+1364) csr ints
//     [133120,+131072) wcat bf16 (2 layers * 128 j * 256 k)
//     [264192,+20480) Ag bf16 [80][128] (graph multiplicity matrix)
#define WS_CSR_OFF  131072
#define WS_W_OFF    133120
#define WS_AG_OFF   264192

typedef __attribute__((ext_vector_type(8))) short bf16x8;
typedef __attribute__((ext_vector_type(4))) float f32x4;

// XOR swizzle (T2): spreads 16-row column reads across 8 16B slots
#define SWZ256(r, cb) (((r) * 256) + ((cb) ^ (((r) & 7) << 4)))
#define SWZ512(r, cb) (((r) * 512) + ((cb) ^ (((r) & 7) << 4)))
#define MFMA16(a, bb, c) __builtin_amdgcn_mfma_f32_16x16x32_bf16((a), (bb), (c), 0, 0, 0)

__device__ __forceinline__ short bf16_rne(float x) {
  unsigned u = __builtin_bit_cast(unsigned, x);
  u += 0x7FFFu + ((u >> 16) & 1u);
  return (short)(u >> 16);
}

__global__ void prep_kernel(const int* __restrict__ edge_index,
                            const float* __restrict__ W2r, const float* __restrict__ W2o,
                            const float* __restrict__ W3r, const float* __restrict__ W3o,
                            int* __restrict__ csr, short* __restrict__ wcat,
                            short* __restrict__ agw) {
  // wcat[layer][j][k]: k<128 -> Wrel[j][k], k>=128 -> Wroot[j][k-128]
  int gid = blockIdx.x * blockDim.x + threadIdx.x;
  for (int e = gid; e < 2 * F_ * 256; e += gridDim.x * blockDim.x) {
    int layer = e >> 15, idx = e & 32767;
    int j = idx >> 8, k = idx & 255;
    const float* Wr = layer ? W3r : W2r;
    const float* Wo = layer ? W3o : W2o;
    float v = (k < F_) ? Wr[j * F_ + k] : Wo[j * F_ + (k - F_)];
    wcat[e] = bf16_rne(v);
  }
  __shared__ unsigned short cnt[80 * 128];
  __shared__ int src_s[E_], dst_s[E_], cc[N_], offs[N_ + 1];
  if (blockIdx.x == 0) {
    int t = threadIdx.x;
    for (int i = t; i < 80 * 128; i += blockDim.x) cnt[i] = 0;
    for (int e = t; e < E_; e += blockDim.x) { src_s[e] = edge_index[e]; dst_s[e] = edge_index[E_ + e]; }
    for (int n = t; n < N_; n += blockDim.x) cc[n] = 0;
    __syncthreads();
    if (t == 0) {
      for (int e = 0; e < E_; ++e) { cnt[dst_s[e] * 128 + src_s[e]]++; cc[dst_s[e]]++; }
      offs[0] = 0;
      for (int n = 0; n < N_; ++n) offs[n + 1] = offs[n] + cc[n];
      for (int n = 0; n < N_; ++n) cc[n] = offs[n];
      for (int e = 0; e < E_; ++e) { int d = dst_s[e]; csr[N_ + 1 + cc[d]++] = src_s[e]; }
      for (int n = 0; n <= N_; ++n) csr[n] = offs[n];
    }
    __syncthreads();
    for (int i = t; i < 80 * 128; i += blockDim.x) agw[i] = bf16_rne((float)cnt[i]);
  }
}

__launch_bounds__(512, 2)
__global__ void fused_kernel(
    const float* __restrict__ x, const float* __restrict__ adj, const float* __restrict__ s,
    const float* __restrict__ pos,
    const float* __restrict__ W1r, const float* __restrict__ W1o, const float* __restrict__ b1,
    const float* __restrict__ b2f, const float* __restrict__ b3f,
    const short* __restrict__ wcat, const short* __restrict__ agw,
    float* __restrict__ out, const int* __restrict__ csr, double* __restrict__ partials)
{
  __shared__ __align__(16) short Hn[80 * 256];    // node-major cat: [n][0..127]=agg, [128..255]=h
  __shared__ __align__(16) short HT[128 * 128];   // feature-major h [f][n]
  __shared__ __align__(16) short Ag[80 * 128];    // graph matrix [dst][src], zero-padded
  __shared__ __align__(16) short AdjB[80 * 128];  // batch adj bf16 [n][m], zero-padded
  __shared__ __align__(16) short ssmT[16 * 128];  // softmax(s)^T [c][n], zero-padded
  __shared__ __align__(16) short TT[16 * 128];    // (adj@S)^T [c][n], zero-padded
  __shared__ float xb[N_ * FIN], axb[N_ * FIN];
  __shared__ int offs[N_ + 1], srcs[E_];
  __shared__ double red[16];

  const int b = blockIdx.x, tid = threadIdx.x;
  const int lane = tid & 63, wave = tid >> 6;
  const int l15 = lane & 15, lg = lane >> 4;
  const int f = tid & 127, ng = tid >> 7;
  const int j0 = wave * 16;

  int4 zz; zz.x = 0; zz.y = 0; zz.z = 0; zz.w = 0;

  // ---- Pz: zero all K-pad regions (0 x NaN = NaN hazard with stale LDS) ----
  for (int i = tid; i < 1024; i += 512)           // HT cols [64,128)
    *(int4*)((char*)HT + SWZ256(i >> 3, 128 + (i & 7) * 16)) = zz;
  for (int i = tid; i < 128; i += 512)            // TT cols [64,128)
    *(int4*)((char*)TT + SWZ256(i >> 3, 128 + (i & 7) * 16)) = zz;
  for (int i = tid; i < 128; i += 512)            // ssmT cols [64,128)
    *(int4*)((char*)ssmT + SWZ256(i >> 3, 128 + (i & 7) * 16)) = zz;
  for (int i = tid; i < 1280; i += 512)           // AdjB all
    *(int4*)((char*)AdjB + SWZ256(i >> 4, (i & 15) * 16)) = zz;
  __syncthreads();

  // ---- P0: fills ----
  for (int i = tid; i < N_ + 1; i += 512) offs[i] = csr[i];
  for (int i = tid; i < E_; i += 512) srcs[i] = csr[N_ + 1 + i];
  for (int i = tid; i < N_ * FIN; i += 512) xb[i] = x[(size_t)b * N_ * FIN + i];
  // Ag copy: [80][128] bf16 = 1280 int4 chunks; row = i>>4, 16B chunk = i&15
  for (int i = tid; i < 1280; i += 512)
    *(int4*)((char*)Ag + SWZ256(i >> 4, (i & 15) * 16)) = ((const int4*)agw)[i];
  // AdjB fill + sum(adj^2)
  float sadj2 = 0.f;
  const float* adjb = &adj[(size_t)b * N_ * N_];
  for (int q = tid; q < N_ * N_; q += 512) {
    int n = q / N_, m = q - n * N_;
    float v = adjb[q];
    sadj2 += v * v;
    *(short*)((char*)AdjB + SWZ256(n, m * 2)) = bf16_rne(v);
  }
  // softmax rows -> ssmT (bf16), ent via m + logZ - sum(p*s)
  float entPart = 0.f;
  if (tid < N_) {
    const float* srow = &s[((size_t)b * N_ + tid) * C_];
    float sv[16], ev[16];
    float mx = -1e30f;
#pragma unroll
    for (int c = 0; c < 16; ++c) { sv[c] = srow[c]; mx = fmaxf(mx, sv[c]); }
    float sum = 0.f;
#pragma unroll
    for (int c = 0; c < 16; ++c) { ev[c] = expf(sv[c] - mx); sum += ev[c]; }
    float inv = 1.f / sum, ps = 0.f;
#pragma unroll
    for (int c = 0; c < 16; ++c) {
      float pv = ev[c] * inv;
      ps += pv * sv[c];
      *(short*)((char*)ssmT + SWZ256(c, tid * 2)) = bf16_rne(pv);
    }
    entPart = (mx + logf(sum)) - ps;
  }
  __syncthreads();

  // ---- P1: layer-1 edge aggregation on [68,2] (tiny, VALU) ----
  if (tid < N_) {
    float a0 = 0, a1 = 0;
    for (int e = offs[tid]; e < offs[tid + 1]; ++e) {
      int sr = srcs[e];
      a0 += xb[sr * 2]; a1 += xb[sr * 2 + 1];
    }
    axb[tid * 2] = a0; axb[tid * 2 + 1] = a1;
  }
  __syncthreads();

  // ---- P2: layer 1 (K=2, VALU) -> Hn root-half + HT ----
  {
    float wr0 = W1r[f * 2], wr1 = W1r[f * 2 + 1];
    float wo0 = W1o[f * 2], wo1 = W1o[f * 2 + 1];
    float bv = b1[f];
    for (int i = 0; i < 17; ++i) {
      int n = ng * 17 + i;
      float v = axb[n * 2] * wr0 + axb[n * 2 + 1] * wr1 + xb[n * 2] * wo0 + xb[n * 2 + 1] * wo1 + bv;
      v = v > 0.f ? v : 0.f;
      short hv = bf16_rne(v);
      *(short*)((char*)Hn + SWZ512(n, 256 + f * 2)) = hv;
      *(short*)((char*)HT + SWZ256(f, n * 2)) = hv;
    }
  }
  __syncthreads();

  // ---- P3: agg2 = Ag @ h1 (MFMA) -> Hn agg-half ----
  {
    bf16x8 Bh[3];
#pragma unroll
    for (int ks = 0; ks < 3; ++ks)
      Bh[ks] = *(const bf16x8*)((const char*)HT + SWZ256(j0 + l15, ks * 64 + 16 * lg));
#pragma unroll
    for (int mt = 0; mt < 5; ++mt) {
      f32x4 acc = {0.f, 0.f, 0.f, 0.f};
#pragma unroll
      for (int ks = 0; ks < 3; ++ks)
        acc = MFMA16(*(const bf16x8*)((const char*)Ag + SWZ256(mt * 16 + l15, ks * 64 + 16 * lg)), Bh[ks], acc);
#pragma unroll
      for (int r = 0; r < 4; ++r) {
        int n = mt * 16 + lg * 4 + r;
        if (n < N_) *(short*)((char*)Hn + SWZ512(n, (j0 + l15) * 2)) = bf16_rne(acc[r]);
      }
    }
  }
  __syncthreads();

  // ---- P4: layer 2 (MFMA, K=256), deferred epilogue -> Hn root + HT ----
  {
    f32x4 accL[5];
    bf16x8 Bw[8];
#pragma unroll
    for (int ks = 0; ks < 8; ++ks)
      Bw[ks] = *(const bf16x8*)(wcat + (j0 + l15) * 256 + ks * 32 + 8 * lg);
#pragma unroll
    for (int mt = 0; mt < 5; ++mt) {
      f32x4 acc = {0.f, 0.f, 0.f, 0.f};
#pragma unroll
      for (int ks = 0; ks < 8; ++ks)
        acc = MFMA16(*(const bf16x8*)((const char*)Hn + SWZ512(mt * 16 + l15, ks * 64 + 16 * lg)), Bw[ks], acc);
      accL[mt] = acc;
    }
    __syncthreads();   // all Hn reads done
    float bv = b2f[j0 + l15];
#pragma unroll
    for (int mt = 0; mt < 5; ++mt)
#pragma unroll
      for (int r = 0; r < 4; ++r) {
        int n = mt * 16 + lg * 4 + r;
        if (n < N_) {
          float v = accL[mt][r] + bv;
          v = v > 0.f ? v : 0.f;
          short hv = bf16_rne(v);
          *(short*)((char*)Hn + SWZ512(n, 256 + (j0 + l15) * 2)) = hv;
          *(short*)((char*)HT + SWZ256(j0 + l15, n * 2)) = hv;
        }
      }
  }
  __syncthreads();

  // ---- P5: agg3 = Ag @ h2 -> Hn agg-half ----
  {
    bf16x8 Bh[3];
#pragma unroll
    for (int ks = 0; ks < 3; ++ks)
      Bh[ks] = *(const bf16x8*)((const char*)HT + SWZ256(j0 + l15, ks * 64 + 16 * lg));
#pragma unroll
    for (int mt = 0; mt < 5; ++mt) {
      f32x4 acc = {0.f, 0.f, 0.f, 0.f};
#pragma unroll
      for (int ks = 0; ks < 3; ++ks)
        acc = MFMA16(*(const bf16x8*)((const char*)Ag + SWZ256(mt * 16 + l15, ks * 64 + 16 * lg)), Bh[ks], acc);
#pragma unroll
      for (int r = 0; r < 4; ++r) {
        int n = mt * 16 + lg * 4 + r;
        if (n < N_) *(short*)((char*)Hn + SWZ512(n, (j0 + l15) * 2)) = bf16_rne(acc[r]);
      }
    }
  }
  __syncthreads();

  // ---- P6: layer 3 (MFMA), deferred epilogue -> HT only (h3) ----
  {
    f32x4 accL[5];
    bf16x8 Bw[8];
#pragma unroll
    for (int ks = 0; ks < 8; ++ks)
      Bw[ks] = *(const bf16x8*)(wcat + 32768 + (j0 + l15) * 256 + ks * 32 + 8 * lg);
#pragma unroll
    for (int mt = 0; mt < 5; ++mt) {
      f32x4 acc = {0.f, 0.f, 0.f, 0.f};
#pragma unroll
      for (int ks = 0; ks < 8; ++ks)
        acc = MFMA16(*(const bf16x8*)((const char*)Hn + SWZ512(mt * 16 + l15, ks * 64 + 16 * lg)), Bw[ks], acc);
      accL[mt] = acc;
    }
    __syncthreads();
    float bv = b3f[j0 + l15];
#pragma unroll
    for (int mt = 0; mt < 5; ++mt)
#pragma unroll
      for (int r = 0; r < 4; ++r) {
        int n = mt * 16 + lg * 4 + r;
        if (n < N_) {
          float v = accL[mt][r] + bv;
          v = v > 0.f ? v : 0.f;
          *(short*)((char*)HT + SWZ256(j0 + l15, n * 2)) = bf16_rne(v);
        }
      }
  }
  __syncthreads();

  // ---- P7: pooling MFMAs ----
  float trPart = 0.f, g2Part = 0.f;
  {
    // pooled out (all waves): outT[f][c] = sum_n h3T[f][n] * S[n][c]
    f32x4 acc = {0.f, 0.f, 0.f, 0.f};
#pragma unroll
    for (int ks = 0; ks < 3; ++ks)
      acc = MFMA16(*(const bf16x8*)((const char*)HT + SWZ256(j0 + l15, ks * 64 + 16 * lg)),
                   *(const bf16x8*)((const char*)ssmT + SWZ256(l15, ks * 64 + 16 * lg)), acc);
    float4 st; st.x = acc[0]; st.y = acc[1]; st.z = acc[2]; st.w = acc[3];
    *(float4*)&out[OUT_OFF + (size_t)b * C_ * F_ + l15 * F_ + j0 + lg * 4] = st;
  }
  if (wave < 5) {
    // T = adj @ S -> TT[c][n] (waves 0..4 take m-tiles)
    f32x4 acc = {0.f, 0.f, 0.f, 0.f};
#pragma unroll
    for (int ks = 0; ks < 3; ++ks)
      acc = MFMA16(*(const bf16x8*)((const char*)AdjB + SWZ256(wave * 16 + l15, ks * 64 + 16 * lg)),
                   *(const bf16x8*)((const char*)ssmT + SWZ256(l15, ks * 64 + 16 * lg)), acc);
#pragma unroll
    for (int r = 0; r < 4; ++r) {
      int n = wave * 16 + lg * 4 + r;
      if (n < N_) *(short*)((char*)TT + SWZ256(l15, n * 2)) = bf16_rne(acc[r]);
    }
  } else if (wave == 5) {
    // G = S^T S ; ||G||_F^2
    f32x4 acc = {0.f, 0.f, 0.f, 0.f};
#pragma unroll
    for (int ks = 0; ks < 3; ++ks) {
      bf16x8 a = *(const bf16x8*)((const char*)ssmT + SWZ256(l15, ks * 64 + 16 * lg));
      acc = MFMA16(a, a, acc);
    }
#pragma unroll
    for (int r = 0; r < 4; ++r) g2Part += acc[r] * acc[r];
  }
  __syncthreads();

  // ---- P8: out_adj = S^T T (wave 0) + trace; pos passthrough ----
  if (wave == 0) {
    f32x4 acc = {0.f, 0.f, 0.f, 0.f};
#pragma unroll
    for (int ks = 0; ks < 3; ++ks)
      acc = MFMA16(*(const bf16x8*)((const char*)ssmT + SWZ256(l15, ks * 64 + 16 * lg)),
                   *(const bf16x8*)((const char*)TT + SWZ256(l15, ks * 64 + 16 * lg)), acc);
#pragma unroll
    for (int r = 0; r < 4; ++r) {
      int c = lg * 4 + r;
      out[ADJ_OFF + (size_t)b * 256 + c * 16 + l15] = acc[r];
      if (c == l15) trPart += acc[r];
    }
  }
  for (int i = tid; i < N_ * FIN; i += 512)
    out[POS_OFF + (size_t)b * N_ * FIN + i] = pos[(size_t)b * N_ * FIN + i];

  // ---- P9: loss reductions: link = sum(adj^2) - 2*tr + ||G||^2 ----
  double lk = (double)sadj2 - 2.0 * (double)trPart + (double)g2Part;
  double en = (double)entPart;
  for (int o = 32; o > 0; o >>= 1) { lk += __shfl_down(lk, o); en += __shfl_down(en, o); }
  if ((tid & 63) == 0) { red[wave] = lk; red[8 + wave] = en; }
  __syncthreads();
  if (tid == 0) {
    double L = 0, En = 0;
    for (int w = 0; w < 8; ++w) { L += red[w]; En += red[8 + w]; }
    partials[2 * b] = L;
    partials[2 * b + 1] = En;
  }
}

__global__ void finalize_kernel(const double* __restrict__ partials, float* __restrict__ out) {
  __shared__ double red[16];
  int tid = threadIdx.x;
  double L = 0, En = 0;
  for (int i = tid; i < B_; i += 512) { L += partials[2 * i]; En += partials[2 * i + 1]; }
  for (int o = 32; o > 0; o >>= 1) { L += __shfl_down(L, o); En += __shfl_down(En, o); }
  if ((tid & 63) == 0) { red[tid >> 6] = L; red[8 + (tid >> 6)] = En; }
  __syncthreads();
  if (tid == 0) {
    double Ls = 0, Es = 0;
    for (int w = 0; w < 8; ++w) { Ls += red[w]; Es += red[8 + w]; }
    out[LINK_IDX] = (float)(sqrt(Ls) / (double)((size_t)B_ * N_ * N_));
    out[ENT_IDX] = (float)(Es / (double)((size_t)B_ * N_));
  }
}

extern "C" void kernel_launch(void* const* d_in, const int* in_sizes, int n_in,
                              void* d_out, int out_size, void* d_ws, size_t ws_size,
                              hipStream_t stream) {
  const float* x   = (const float*)d_in[0];
  const int*   ei  = (const int*)d_in[1];
  const float* adj = (const float*)d_in[2];
  const float* s   = (const float*)d_in[3];
  const float* pos = (const float*)d_in[4];
  const float* W1r = (const float*)d_in[5];
  const float* W1o = (const float*)d_in[6];
  const float* b1  = (const float*)d_in[7];
  const float* W2r = (const float*)d_in[8];
  const float* W2o = (const float*)d_in[9];
  const float* b2  = (const float*)d_in[10];
  const float* W3r = (const float*)d_in[11];
  const float* W3o = (const float*)d_in[12];
  const float* b3  = (const float*)d_in[13];

  float* out = (float*)d_out;
  double* partials = (double*)d_ws;
  int* csr = (int*)((char*)d_ws + WS_CSR_OFF);
  short* wcat = (short*)((char*)d_ws + WS_W_OFF);
  short* agw  = (short*)((char*)d_ws + WS_AG_OFF);

  prep_kernel<<<65, 512, 0, stream>>>(ei, W2r, W2o, W3r, W3o, csr, wcat, agw);
  fused_kernel<<<B_, 512, 0, stream>>>(x, adj, s, pos, W1r, W1o, b1, b2, b3,
                                       wcat, agw, out, csr, partials);
  finalize_kernel<<<1, 512, 0, stream>>>(partials, out);
}